// Round 1
// baseline (148.764 us; speedup 1.0000x reference)
//
#include <hip/hip_runtime.h>
#include <cstdint>
#include <cstddef>

constexpr int Bn = 64;     // batch
constexpr int Nn = 1024;   // nodes per graph
constexpr int Dn = 1024;   // input feature dim
constexpr int Cn = 128;    // hidden channels
constexpr int En = 16384;  // edges per graph

typedef short s16x8 __attribute__((ext_vector_type(8)));   // 8 bf16 = 4 VGPR (MFMA A/B frag)
typedef float f32x4 __attribute__((ext_vector_type(4)));   // MFMA C/D frag

__device__ __forceinline__ uint32_t f2bf(float f) {        // fp32 -> bf16 bits, RNE
    uint32_t u = __float_as_uint(f);
    return (u + 0x7fffu + ((u >> 16) & 1u)) >> 16;
}

// ---------------- K1: embed partial dots (blocks 0..255) + Wc -> bf16 transpose (256..319) ----------------
__global__ __launch_bounds__(256) void k_prep(const float* __restrict__ x,
                                              const float* __restrict__ We,
                                              const float* __restrict__ Wc,
                                              float* __restrict__ pws,
                                              unsigned short* __restrict__ Wt) {
    int bid = blockIdx.x, tid = threadIdx.x;
    if (bid < 256) {
        __shared__ float sx[256];
        __shared__ float sp[256];
        int b = bid >> 2, q = bid & 3;
        int c = tid & 127, h2 = tid >> 7;
        sx[tid] = x[b * Dn + q * 256 + tid];
        __syncthreads();
        float acc = 0.f;
        int d0 = q * 256 + h2 * 128;
        int dl = h2 * 128;
#pragma unroll 8
        for (int i = 0; i < 128; ++i) acc += sx[dl + i] * We[(d0 + i) * Cn + c];
        sp[h2 * 128 + c] = acc;
        __syncthreads();
        if (h2 == 0) pws[(b * 4 + q) * Cn + c] = sp[c] + sp[128 + c];
    } else {
        int i = (bid - 256) * 256 + tid;        // [0, 16384)
        int n = i >> 7, k = i & 127;
        Wt[i] = (unsigned short)f2bf(Wc[k * Cn + n]);
    }
}

// ---------------- K2: fused single-block graph kernel ----------------
// detect int64 -> stage edges in LDS -> hist -> scan -> scatter(+edeg) -> levels F3/F2 -> g GEMV
__global__ __launch_bounds__(1024) void k_graph(const int* __restrict__ ei32,
                                                const float* __restrict__ pws,
                                                const float* __restrict__ be,
                                                const float* __restrict__ Wc,
                                                int* __restrict__ offsG,
                                                int* __restrict__ ssrc,
                                                float* __restrict__ edeg,
                                                int* __restrict__ L3,
                                                int* __restrict__ L2,
                                                int* __restrict__ meta,
                                                float* __restrict__ g) {
    __shared__ unsigned int sEdge[En];        // 64 KB: src | dst<<16
    __shared__ int sDeg[Nn];                  // 4 KB
    __shared__ int sTmp[Nn];                  // 4 KB (scan)
    __shared__ int sCur[Nn];                  // 4 KB
    __shared__ float eT[Cn][72];              // 36.9 KB: eT[k][b], pad 72 keeps b128 16B-aligned
    __shared__ unsigned char sf3[Nn], sf2[Nn];
    __shared__ int sFlag, c3s, c2s;
    int t = threadIdx.x;

    // init
    sDeg[t] = 0; sf3[t] = 0; sf2[t] = 0;
    if (t == 0) { sFlag = 0; c3s = 0; c2s = 0; }
    __syncthreads();

    // int64-layout detect: int64 => all high words 0; int32 => random values, ~certainly nonzero
    if (ei32[2 * t + 1]) atomicOr(&sFlag, 1);
    __syncthreads();
    bool i64 = (sFlag == 0);

    // stage + histogram
    for (int i = t; i < En; i += 1024) {
        int s = (i64 ? ei32[2 * i] : ei32[i]) & (Nn - 1);
        int d = (i64 ? ei32[2 * (En + i)] : ei32[En + i]) & (Nn - 1);
        sEdge[i] = (unsigned)s | ((unsigned)d << 16);
        atomicAdd(&sDeg[d], 1);
    }
    __syncthreads();

    // inclusive scan (Hillis-Steele)
    int v = sDeg[t];
    sTmp[t] = v;
    __syncthreads();
    for (int off = 1; off < Nn; off <<= 1) {
        int add = (t >= off) ? sTmp[t - off] : 0;
        __syncthreads();
        sTmp[t] += add;
        __syncthreads();
    }
    offsG[t + 1] = sTmp[t];
    if (t == 0) offsG[0] = 0;
    sCur[t] = sTmp[t] - v;                    // exclusive prefix
    __syncthreads();

    // scatter to CSR + per-edge src-degree; mark F3 (in-neighbors of node 0)
    for (int i = t; i < En; i += 1024) {
        unsigned e = sEdge[i];
        int s = e & 0xffff, d = e >> 16;
        int pos = atomicAdd(&sCur[d], 1);
        ssrc[pos] = s;
        edeg[pos] = (float)sDeg[s];
        if (d == 0) sf3[s] = 1;
    }
    __syncthreads();

    // F2 = in-neighbors of F3
    for (int i = t; i < En; i += 1024) {
        unsigned e = sEdge[i];
        if (sf3[e >> 16]) sf2[e & 0xffff] = 1;
    }
    __syncthreads();
    if (sf3[t]) { int p = atomicAdd(&c3s, 1); L3[p] = t; }
    if (sf2[t]) { int p = atomicAdd(&c2s, 1); L2[p] = t; }

    // e[b][c] = relu(sum_q pws + be) -> eT[c][b]
    {
        int c = t & 127;
        for (int b = t >> 7; b < Bn; b += 8) {
            float e4 = pws[(b * 4 + 0) * Cn + c] + pws[(b * 4 + 1) * Cn + c] +
                       pws[(b * 4 + 2) * Cn + c] + pws[(b * 4 + 3) * Cn + c] + be[c];
            eT[c][b] = fmaxf(e4, 0.f);
        }
    }
    __syncthreads();
    if (t == 0) { meta[2] = c3s; meta[3] = c2s; }

    // g[b][c] = sum_k eT[k][b] * Wc[k][c]; thread = (c, 8-b slab)
    {
        int c = t & 127, bq = t >> 7;
        float acc[8];
#pragma unroll
        for (int j = 0; j < 8; ++j) acc[j] = 0.f;
        for (int k = 0; k < Cn; ++k) {
            float wv = Wc[k * Cn + c];
            const float4* ep = (const float4*)&eT[k][bq * 8];
            float4 ea = ep[0], eb = ep[1];
            acc[0] += ea.x * wv; acc[1] += ea.y * wv; acc[2] += ea.z * wv; acc[3] += ea.w * wv;
            acc[4] += eb.x * wv; acc[5] += eb.y * wv; acc[6] += eb.z * wv; acc[7] += eb.w * wv;
        }
#pragma unroll
        for (int j = 0; j < 8; ++j) g[(bq * 8 + j) * Cn + c] = acc[j];
    }
}

constexpr int PAD = 136;     // LDS row stride in bf16 elems

// ---------------- K3: conv 1+2 fused, frontier-restricted, tile-loop grid (XCD = b%8) ----------------
__global__ __launch_bounds__(256, 4) void k_conv2L(const float* __restrict__ g,
                                                   float* __restrict__ h2,
                                                   const unsigned short* __restrict__ Wt,
                                                   const float* __restrict__ bc,
                                                   const int* __restrict__ offs,
                                                   const float* __restrict__ edeg,
                                                   const int* __restrict__ L2,
                                                   const int* __restrict__ meta) {
    int bidx = blockIdx.x;
    int tile0 = bidx >> 6, b = bidx & 63;     // blocks with same b stay on XCD b%8
    int cnt2 = meta[3];
    __shared__ unsigned short sSb[32 * PAD];  // 8.7 KB
    __shared__ float sEd[32][64];             // 8 KB
    __shared__ int snode[32], slo[32], scnt[32];
    int tid = threadIdx.x;
    int w = tid >> 6, lane = tid & 63, m = lane & 15, quad = lane >> 4;

    int c2 = tid & 63;
    float gx = g[b * Cn + 2 * c2], gy = g[b * Cn + 2 * c2 + 1];
    float bx = bc[2 * c2], by = bc[2 * c2 + 1];

    // B-fragments from global Wt (32 KB, L2-hot) — tile-invariant, hoisted
    s16x8 bf0[4], bf1[4];
#pragma unroll
    for (int ks = 0; ks < 4; ++ks) {
        int ko = ks * 32 + quad * 8;
        bf0[ks] = *(const s16x8*)&Wt[(w * 32 + m) * Cn + ko];
        bf1[ks] = *(const s16x8*)&Wt[(w * 32 + 16 + m) * Cn + ko];
    }

    for (int tile = tile0; tile * 32 < cnt2; tile += 8) {
        __syncthreads();
        if (tid < 32) {
            int ti = tile * 32 + tid;
            int node = (ti < cnt2) ? L2[ti] : -1;
            snode[tid] = node;
            int lo = (node >= 0) ? offs[node] : 0;
            int hi = (node >= 0) ? offs[node + 1] : 0;
            slo[tid] = lo; scnt[tid] = hi - lo;
        }
        __syncthreads();
#pragma unroll
        for (int r = 0; r < 8; ++r) {
            int row = w * 8 + r;
            int cnt = scnt[row];
            if (lane < cnt && lane < 64) sEd[row][lane] = edeg[slo[row] + lane];
        }
        __syncthreads();
#pragma unroll
        for (int t0 = 0; t0 < 8; ++t0) {
            int row = w * 8 + t0;
            int cnt = scnt[row], lo = slo[row];
            float s0 = 0.f, s1 = 0.f;
            int jm = cnt < 64 ? cnt : 64;
            for (int j = 0; j < jm; ++j) {
                float d = sEd[row][j];
                s0 += fmaxf(fmaf(d, gx, bx), 0.f);
                s1 += fmaxf(fmaf(d, gy, by), 0.f);
            }
            for (int j = 64; j < cnt; ++j) {  // rare overflow tail
                float d = edeg[lo + j];
                s0 += fmaxf(fmaf(d, gx, bx), 0.f);
                s1 += fmaxf(fmaf(d, gy, by), 0.f);
            }
            *(uint32_t*)&sSb[row * PAD + 2 * c2] = f2bf(s0) | (f2bf(s1) << 16);
        }
        __syncthreads();

        f32x4 acc[2][2];
#pragma unroll
        for (int rt = 0; rt < 2; ++rt)
#pragma unroll
            for (int ct = 0; ct < 2; ++ct) acc[rt][ct] = (f32x4){0.f, 0.f, 0.f, 0.f};
#pragma unroll
        for (int ks = 0; ks < 4; ++ks) {
            int ko = ks * 32 + quad * 8;
            s16x8 a0 = *(const s16x8*)&sSb[(0 * 16 + m) * PAD + ko];
            s16x8 a1 = *(const s16x8*)&sSb[(1 * 16 + m) * PAD + ko];
            acc[0][0] = __builtin_amdgcn_mfma_f32_16x16x32_bf16(a0, bf0[ks], acc[0][0], 0, 0, 0);
            acc[0][1] = __builtin_amdgcn_mfma_f32_16x16x32_bf16(a0, bf1[ks], acc[0][1], 0, 0, 0);
            acc[1][0] = __builtin_amdgcn_mfma_f32_16x16x32_bf16(a1, bf0[ks], acc[1][0], 0, 0, 0);
            acc[1][1] = __builtin_amdgcn_mfma_f32_16x16x32_bf16(a1, bf1[ks], acc[1][1], 0, 0, 0);
        }

#pragma unroll
        for (int rt = 0; rt < 2; ++rt)
#pragma unroll
            for (int ct = 0; ct < 2; ++ct) {
                int col = w * 32 + ct * 16 + m;
                float bias = bc[col];
#pragma unroll
                for (int reg = 0; reg < 4; ++reg) {
                    int row = rt * 16 + quad * 4 + reg;
                    int node = snode[row];
                    if (node >= 0)
                        h2[((size_t)b * Nn + node) * Cn + col] = fmaxf(acc[rt][ct][reg] + bias, 0.f);
                }
            }
    }
}

// ---------------- K4: conv 3 (F3 rows, h3 kept in LDS) fused with conv 4 + classifier ----------------
__global__ __launch_bounds__(256) void k_conv34(const float* __restrict__ h2,
                                                const unsigned short* __restrict__ Wt,
                                                const float* __restrict__ bc,
                                                const int* __restrict__ offs,
                                                const int* __restrict__ ssrc,
                                                const int* __restrict__ L3,
                                                const int* __restrict__ meta,
                                                const float* __restrict__ Wc,
                                                const float* __restrict__ Wcls,
                                                const float* __restrict__ bcls,
                                                float* __restrict__ out) {
    __shared__ unsigned short sSb[32 * PAD];  // 8.7 KB
    __shared__ int sIdx[32][64];              // 8 KB
    __shared__ float sH3[32][Cn];             // 16 KB: h3 tile, fp32
    __shared__ short smap[Nn];                // 2 KB: node -> tile row
    __shared__ int snode[32], slo[32], scnt[32];
    __shared__ float sAgg[8][Cn];             // 4 KB
    __shared__ float sred[256];
    __shared__ int sI[256];
    int b = blockIdx.x, tid = threadIdx.x;
    int cnt3 = meta[2];
    int e1 = offs[1];                         // edges into node 0
    int lim = e1 < 256 ? e1 : 256;
    if (tid < lim) sI[tid] = ssrc[tid];

    int w = tid >> 6, lane = tid & 63, m = lane & 15, quad = lane >> 4;
    s16x8 bf0[4], bf1[4];
#pragma unroll
    for (int ks = 0; ks < 4; ++ks) {
        int ko = ks * 32 + quad * 8;
        bf0[ks] = *(const s16x8*)&Wt[(w * 32 + m) * Cn + ko];
        bf1[ks] = *(const s16x8*)&Wt[(w * 32 + 16 + m) * Cn + ko];
    }
    int c4 = tid & 31, u = tid >> 5;
    const float4* hb4 = (const float4*)(h2 + (size_t)b * (Nn * Cn));
    float4 aAgg = {0.f, 0.f, 0.f, 0.f};

    for (int tile = 0; tile * 32 < cnt3; ++tile) {
        __syncthreads();                      // protects sI (iter 0) and sH3/smap reuse
#pragma unroll
        for (int r = 0; r < 4; ++r) smap[tid + 256 * r] = -1;
        if (tid < 32) {
            int ti = tile * 32 + tid;
            int node = (ti < cnt3) ? L3[ti] : -1;
            snode[tid] = node;
            int lo = (node >= 0) ? offs[node] : 0;
            int hi = (node >= 0) ? offs[node + 1] : 0;
            slo[tid] = lo; scnt[tid] = hi - lo;
        }
        __syncthreads();
        if (tid < 32 && snode[tid] >= 0) smap[snode[tid]] = (short)tid;
#pragma unroll
        for (int r = 0; r < 8; ++r) {
            int row = w * 8 + r;
            int cnt = scnt[row];
            if (lane < cnt && lane < 64) sIdx[row][lane] = ssrc[slo[row] + lane];
        }
        __syncthreads();

        // gather h2 rows -> bf16 A-tile
#pragma unroll
        for (int t0 = 0; t0 < 4; ++t0) {
            int row = u * 4 + t0;
            int cnt = scnt[row], lo = slo[row];
            float4 a = {0.f, 0.f, 0.f, 0.f};
            int jm = cnt < 64 ? cnt : 64;
            for (int j = 0; j < jm; ++j) {
                float4 v = hb4[sIdx[row][j] * 32 + c4];
                a.x += v.x; a.y += v.y; a.z += v.z; a.w += v.w;
            }
            for (int j = 64; j < cnt; ++j) {  // rare overflow tail
                float4 v = hb4[ssrc[lo + j] * 32 + c4];
                a.x += v.x; a.y += v.y; a.z += v.z; a.w += v.w;
            }
            uint2 pk;
            pk.x = f2bf(a.x) | (f2bf(a.y) << 16);
            pk.y = f2bf(a.z) | (f2bf(a.w) << 16);
            *(uint2*)&sSb[row * PAD + c4 * 4] = pk;
        }
        __syncthreads();

        f32x4 acc[2][2];
#pragma unroll
        for (int rt = 0; rt < 2; ++rt)
#pragma unroll
            for (int ct = 0; ct < 2; ++ct) acc[rt][ct] = (f32x4){0.f, 0.f, 0.f, 0.f};
#pragma unroll
        for (int ks = 0; ks < 4; ++ks) {
            int ko = ks * 32 + quad * 8;
            s16x8 a0 = *(const s16x8*)&sSb[(0 * 16 + m) * PAD + ko];
            s16x8 a1 = *(const s16x8*)&sSb[(1 * 16 + m) * PAD + ko];
            acc[0][0] = __builtin_amdgcn_mfma_f32_16x16x32_bf16(a0, bf0[ks], acc[0][0], 0, 0, 0);
            acc[0][1] = __builtin_amdgcn_mfma_f32_16x16x32_bf16(a0, bf1[ks], acc[0][1], 0, 0, 0);
            acc[1][0] = __builtin_amdgcn_mfma_f32_16x16x32_bf16(a1, bf0[ks], acc[1][0], 0, 0, 0);
            acc[1][1] = __builtin_amdgcn_mfma_f32_16x16x32_bf16(a1, bf1[ks], acc[1][1], 0, 0, 0);
        }

        // h3 tile stays in LDS (same fp32 values as before)
#pragma unroll
        for (int rt = 0; rt < 2; ++rt)
#pragma unroll
            for (int ct = 0; ct < 2; ++ct) {
                int col = w * 32 + ct * 16 + m;
                float bias = bc[col];
#pragma unroll
                for (int reg = 0; reg < 4; ++reg) {
                    int row = rt * 16 + quad * 4 + reg;
                    sH3[row][col] = fmaxf(acc[rt][ct][reg] + bias, 0.f);
                }
            }
        __syncthreads();

        // conv4 aggregation: per-edge (handles multiplicity), restricted to this tile's rows
        for (int j = u; j < lim; j += 8) {
            int r2 = smap[sI[j]];
            if (r2 >= 0) {
                float4 v = *(const float4*)&sH3[r2][c4 * 4];
                aAgg.x += v.x; aAgg.y += v.y; aAgg.z += v.z; aAgg.w += v.w;
            }
        }
        for (int j = 256 + u; j < e1; j += 8) {  // rare overflow tail
            int r2 = smap[ssrc[j]];
            if (r2 >= 0) {
                float4 v = *(const float4*)&sH3[r2][c4 * 4];
                aAgg.x += v.x; aAgg.y += v.y; aAgg.z += v.z; aAgg.w += v.w;
            }
        }
    }

    *(float4*)&sAgg[u][c4 * 4] = aAgg;
    __syncthreads();
    int c = tid & 127, half = tid >> 7;
    if (tid < 128) {
        float s = sAgg[0][c];
#pragma unroll
        for (int q2 = 1; q2 < 8; ++q2) s += sAgg[q2][c];
        sAgg[0][c] = s;
    }
    __syncthreads();
    // split-k GEMV: 1x128 @ Wc (fp32 exact)
    float s = 0.f;
    int k0 = half * 64;
#pragma unroll 8
    for (int k = k0; k < k0 + 64; ++k) s += sAgg[0][k] * Wc[k * Cn + c];
    sred[tid] = s;
    __syncthreads();
    if (tid < 128) {
        float val = fmaxf(sred[c] + sred[128 + c] + bc[c], 0.f);
        sred[tid] = val * Wcls[c];
    }
    __syncthreads();
    for (int st = 64; st > 0; st >>= 1) {
        if (tid < st) sred[tid] += sred[tid + st];
        __syncthreads();
    }
    if (tid == 0) out[b] = sred[0] + bcls[0];
}

extern "C" void kernel_launch(void* const* d_in, const int* in_sizes, int n_in,
                              void* d_out, int out_size, void* d_ws, size_t ws_size,
                              hipStream_t stream) {
    const float* x    = (const float*)d_in[0];
    const int*   ei32 = (const int*)d_in[1];
    const float* We   = (const float*)d_in[2];
    const float* be   = (const float*)d_in[3];
    const float* Wc   = (const float*)d_in[4];
    const float* bc   = (const float*)d_in[5];
    const float* Wcls = (const float*)d_in[6];
    const float* bcls = (const float*)d_in[7];
    float* out = (float*)d_out;

    // ---- workspace layout (unused slots kept for address stability) ----
    // 0        g       32768   (B x C fp32)
    // 36864    meta     4096   (meta[2]=|F3|; meta[3]=|F2|)
    // 40960    offs     8192
    // 53248    ssrc    65536
    // 118784   edeg    65536   (fp32 degree per CSR-ordered edge)
    // 184320   L3       4096
    // 188416   L2       4096
    // 192512   Wt      32768   (128x128 bf16, transposed)
    // 225280   pws    131072   (embed partials)
    // 356352   h2full  33554432 (fp32, sparse-filled at F2 rows)
    char* ws = (char*)d_ws;
    float*          g      = (float*)(ws + 0);
    int*            meta   = (int*)(ws + 36864);
    int*            offs   = (int*)(ws + 40960);
    int*            ssrc   = (int*)(ws + 53248);
    float*          edeg   = (float*)(ws + 118784);
    int*            L3     = (int*)(ws + 184320);
    int*            L2     = (int*)(ws + 188416);
    unsigned short* Wt     = (unsigned short*)(ws + 192512);
    float*          pws    = (float*)(ws + 225280);
    float*          h2full = (float*)(ws + 356352);

    k_prep<<<320, 256, 0, stream>>>(x, We, Wc, pws, Wt);
    k_graph<<<1, 1024, 0, stream>>>(ei32, pws, be, Wc, offs, ssrc, edeg, L3, L2, meta, g);
    k_conv2L<<<8 * Bn, 256, 0, stream>>>(g, h2full, Wt, bc, offs, edeg, L2, meta);
    k_conv34<<<Bn, 256, 0, stream>>>(h2full, Wt, bc, offs, ssrc, L3, meta, Wc, Wcls, bcls, out);
}

// Round 2
// 129.072 us; speedup vs baseline: 1.1526x; 1.1526x over previous
//
#include <hip/hip_runtime.h>
#include <cstdint>
#include <cstddef>

constexpr int Bn = 64;     // batch
constexpr int Nn = 1024;   // nodes per graph
constexpr int Dn = 1024;   // input feature dim
constexpr int Cn = 128;    // hidden channels
constexpr int En = 16384;  // edges per graph

typedef short s16x8 __attribute__((ext_vector_type(8)));   // 8 bf16 = 4 VGPR (MFMA A/B frag)
typedef float f32x4 __attribute__((ext_vector_type(4)));   // MFMA C/D frag

__device__ __forceinline__ uint32_t f2bf(float f) {        // fp32 -> bf16 bits, RNE
    uint32_t u = __float_as_uint(f);
    return (u + 0x7fffu + ((u >> 16) & 1u)) >> 16;
}

// ---------------- K1: embed partials (0..255) | Wt transpose (256..319) | hist+pack+F3 (320..335) ----
// Hist uses per-block LDS histogram -> hists[blk][n] (plain stores, no pre-zeroed global counters).
// int64-layout detect is per-block (1024 sampled high dwords; int32 data ~never all-zero).
// F3 flag semantics: set == store 1, test == (==1); ws poison (0xAA) reads as unset. No zeroing pass.
__global__ __launch_bounds__(256) void k_prep(const float* __restrict__ x,
                                              const float* __restrict__ We,
                                              const float* __restrict__ Wc,
                                              const int* __restrict__ ei32,
                                              float* __restrict__ pws,
                                              unsigned short* __restrict__ Wt,
                                              unsigned int* __restrict__ epk,
                                              int* __restrict__ hists,
                                              int* __restrict__ f3) {
    int bid = blockIdx.x, tid = threadIdx.x;
    if (bid < 256) {
        __shared__ float sx[256];
        __shared__ float sp[256];
        int b = bid >> 2, q = bid & 3;
        int c = tid & 127, h2 = tid >> 7;
        sx[tid] = x[b * Dn + q * 256 + tid];
        __syncthreads();
        float acc = 0.f;
        int d0 = q * 256 + h2 * 128;
        int dl = h2 * 128;
#pragma unroll 8
        for (int i = 0; i < 128; ++i) acc += sx[dl + i] * We[(d0 + i) * Cn + c];
        sp[h2 * 128 + c] = acc;
        __syncthreads();
        if (h2 == 0) pws[(b * 4 + q) * Cn + c] = sp[c] + sp[128 + c];
    } else if (bid < 320) {
        int i = (bid - 256) * 256 + tid;        // [0, 16384)
        int n = i >> 7, k = i & 127;
        Wt[i] = (unsigned short)f2bf(Wc[k * Cn + n]);
    } else {
        int hb = bid - 320;                     // 16 hist blocks, 1024 edges each
        __shared__ int hloc[Nn];
        __shared__ int det;
#pragma unroll
        for (int r = 0; r < 4; ++r) hloc[r * 256 + tid] = 0;
        if (tid == 0) det = 0;
        __syncthreads();
        int base = hb * 1024;
        int hw = 0;
#pragma unroll
        for (int r = 0; r < 4; ++r) { int i = base + r * 256 + tid; hw |= ei32[2 * i + 1]; }
        if (hw) atomicOr(&det, 1);
        __syncthreads();
        bool i64 = (det == 0);
#pragma unroll
        for (int r = 0; r < 4; ++r) {
            int i = base + r * 256 + tid;
            int s, d;
            if (i64) {
                s = ((const int2*)ei32)[i].x & (Nn - 1);        // coalesced 8B loads
                d = ((const int2*)ei32)[En + i].x & (Nn - 1);
            } else {
                s = ei32[i] & (Nn - 1);
                d = ei32[En + i] & (Nn - 1);
            }
            epk[i] = (unsigned)s | ((unsigned)d << 16);
            atomicAdd(&hloc[d], 1);
            if (d == 0) f3[s] = 1;              // benign race: all writers store 1
        }
        __syncthreads();
#pragma unroll
        for (int r = 0; r < 4; ++r) hists[hb * Nn + r * 256 + tid] = hloc[r * 256 + tid];
    }
}

// ---------------- K2: concurrent roles — scan(b0) | F2 mark(b1..16) | L3 compact(b17) | g GEMV(b18..25) ----
__global__ __launch_bounds__(1024) void k_mid(const int* __restrict__ hists,
                                              const unsigned int* __restrict__ epk,
                                              const int* __restrict__ f3,
                                              int* __restrict__ f2,
                                              int* __restrict__ indeg,
                                              int* __restrict__ offs,
                                              int* __restrict__ cursor,
                                              int* __restrict__ L3,
                                              int* __restrict__ meta,
                                              const float* __restrict__ pws,
                                              const float* __restrict__ be,
                                              const float* __restrict__ Wc,
                                              float* __restrict__ g) {
    int bid = blockIdx.x, t = threadIdx.x;
    if (bid == 0) {
        // sum 16 partial hists -> indeg; Hillis-Steele inclusive scan -> offs/cursor
        __shared__ int tmp[Nn];
        int v = 0;
#pragma unroll
        for (int h = 0; h < 16; ++h) v += hists[h * Nn + t];
        indeg[t] = v;
        tmp[t] = v;
        __syncthreads();
        for (int off = 1; off < Nn; off <<= 1) {
            int add = (t >= off) ? tmp[t - off] : 0;
            __syncthreads();
            tmp[t] += add;
            __syncthreads();
        }
        offs[t + 1] = tmp[t];
        if (t == 0) offs[0] = 0;
        cursor[t] = tmp[t] - v;                 // exclusive prefix
    } else if (bid <= 16) {
        int i = (bid - 1) * 1024 + t;
        unsigned e = epk[i];
        if (f3[e >> 16] == 1) f2[e & 0xffff] = 1;
    } else if (bid == 17) {
        __shared__ int c3;
        if (t == 0) c3 = 0;
        __syncthreads();
        if (f3[t] == 1) { int p = atomicAdd(&c3, 1); L3[p] = t; }
        __syncthreads();
        if (t == 0) meta[2] = c3;
    } else {
        // g[b][c] = sum_k relu(e)[b][k] * Wc[k][c]; 8 blocks x 8 b each
        __shared__ float se[8][Cn];
        int blk = bid - 18, bi = t >> 7, c = t & 127, b = blk * 8 + bi;
        float e4 = pws[(b * 4 + 0) * Cn + c] + pws[(b * 4 + 1) * Cn + c] +
                   pws[(b * 4 + 2) * Cn + c] + pws[(b * 4 + 3) * Cn + c] + be[c];
        se[bi][c] = fmaxf(e4, 0.f);
        __syncthreads();
        float acc = 0.f;
#pragma unroll 8
        for (int k = 0; k < Cn; ++k) acc += se[bi][k] * Wc[k * Cn + c];
        g[b * Cn + c] = acc;
    }
}

// ---------------- K3: CSR scatter (b0..15) | L2 compact (b16) ----------------
__global__ __launch_bounds__(1024) void k_scatter(const unsigned int* __restrict__ epk,
                                                  const int* __restrict__ indeg,
                                                  int* __restrict__ cursor,
                                                  int* __restrict__ ssrc,
                                                  float* __restrict__ edeg,
                                                  const int* __restrict__ f2,
                                                  int* __restrict__ L2,
                                                  int* __restrict__ meta) {
    int bid = blockIdx.x, t = threadIdx.x;
    if (bid < 16) {
        int i = bid * 1024 + t;
        unsigned e = epk[i];
        int s = e & 0xffff, d = e >> 16;
        int pos = atomicAdd(&cursor[d], 1);
        ssrc[pos] = s;
        edeg[pos] = (float)indeg[s];
    } else {
        __shared__ int c2;
        if (t == 0) c2 = 0;
        __syncthreads();
        if (f2[t] == 1) { int p = atomicAdd(&c2, 1); L2[p] = t; }
        __syncthreads();
        if (t == 0) meta[3] = c2;
    }
}

constexpr int PAD = 136;     // LDS row stride in bf16 elems

// ---------------- K4: conv 1+2 fused, frontier-restricted, tile-loop grid (XCD = b%8) ----------------
__global__ __launch_bounds__(256, 4) void k_conv2L(const float* __restrict__ g,
                                                   float* __restrict__ h2,
                                                   const unsigned short* __restrict__ Wt,
                                                   const float* __restrict__ bc,
                                                   const int* __restrict__ offs,
                                                   const float* __restrict__ edeg,
                                                   const int* __restrict__ L2,
                                                   const int* __restrict__ meta) {
    int bidx = blockIdx.x;
    int tile0 = bidx >> 6, b = bidx & 63;     // blocks with same b stay on XCD b%8
    int cnt2 = meta[3];
    __shared__ unsigned short sSb[32 * PAD];  // 8.7 KB
    __shared__ float sEd[32][64];             // 8 KB
    __shared__ int snode[32], slo[32], scnt[32];
    int tid = threadIdx.x;
    int w = tid >> 6, lane = tid & 63, m = lane & 15, quad = lane >> 4;

    int c2 = tid & 63;
    float gx = g[b * Cn + 2 * c2], gy = g[b * Cn + 2 * c2 + 1];
    float bx = bc[2 * c2], by = bc[2 * c2 + 1];

    // B-fragments from global Wt (32 KB, L2-hot) — tile-invariant, hoisted
    s16x8 bf0[4], bf1[4];
#pragma unroll
    for (int ks = 0; ks < 4; ++ks) {
        int ko = ks * 32 + quad * 8;
        bf0[ks] = *(const s16x8*)&Wt[(w * 32 + m) * Cn + ko];
        bf1[ks] = *(const s16x8*)&Wt[(w * 32 + 16 + m) * Cn + ko];
    }

    for (int tile = tile0; tile * 32 < cnt2; tile += 8) {
        __syncthreads();
        if (tid < 32) {
            int ti = tile * 32 + tid;
            int node = (ti < cnt2) ? L2[ti] : -1;
            snode[tid] = node;
            int lo = (node >= 0) ? offs[node] : 0;
            int hi = (node >= 0) ? offs[node + 1] : 0;
            slo[tid] = lo; scnt[tid] = hi - lo;
        }
        __syncthreads();
#pragma unroll
        for (int r = 0; r < 8; ++r) {
            int row = w * 8 + r;
            int cnt = scnt[row];
            if (lane < cnt && lane < 64) sEd[row][lane] = edeg[slo[row] + lane];
        }
        __syncthreads();
#pragma unroll
        for (int t0 = 0; t0 < 8; ++t0) {
            int row = w * 8 + t0;
            int cnt = scnt[row], lo = slo[row];
            float s0 = 0.f, s1 = 0.f;
            int jm = cnt < 64 ? cnt : 64;
            for (int j = 0; j < jm; ++j) {
                float d = sEd[row][j];
                s0 += fmaxf(fmaf(d, gx, bx), 0.f);
                s1 += fmaxf(fmaf(d, gy, by), 0.f);
            }
            for (int j = 64; j < cnt; ++j) {  // rare overflow tail
                float d = edeg[lo + j];
                s0 += fmaxf(fmaf(d, gx, bx), 0.f);
                s1 += fmaxf(fmaf(d, gy, by), 0.f);
            }
            *(uint32_t*)&sSb[row * PAD + 2 * c2] = f2bf(s0) | (f2bf(s1) << 16);
        }
        __syncthreads();

        f32x4 acc[2][2];
#pragma unroll
        for (int rt = 0; rt < 2; ++rt)
#pragma unroll
            for (int ct = 0; ct < 2; ++ct) acc[rt][ct] = (f32x4){0.f, 0.f, 0.f, 0.f};
#pragma unroll
        for (int ks = 0; ks < 4; ++ks) {
            int ko = ks * 32 + quad * 8;
            s16x8 a0 = *(const s16x8*)&sSb[(0 * 16 + m) * PAD + ko];
            s16x8 a1 = *(const s16x8*)&sSb[(1 * 16 + m) * PAD + ko];
            acc[0][0] = __builtin_amdgcn_mfma_f32_16x16x32_bf16(a0, bf0[ks], acc[0][0], 0, 0, 0);
            acc[0][1] = __builtin_amdgcn_mfma_f32_16x16x32_bf16(a0, bf1[ks], acc[0][1], 0, 0, 0);
            acc[1][0] = __builtin_amdgcn_mfma_f32_16x16x32_bf16(a1, bf0[ks], acc[1][0], 0, 0, 0);
            acc[1][1] = __builtin_amdgcn_mfma_f32_16x16x32_bf16(a1, bf1[ks], acc[1][1], 0, 0, 0);
        }

#pragma unroll
        for (int rt = 0; rt < 2; ++rt)
#pragma unroll
            for (int ct = 0; ct < 2; ++ct) {
                int col = w * 32 + ct * 16 + m;
                float bias = bc[col];
#pragma unroll
                for (int reg = 0; reg < 4; ++reg) {
                    int row = rt * 16 + quad * 4 + reg;
                    int node = snode[row];
                    if (node >= 0)
                        h2[((size_t)b * Nn + node) * Cn + col] = fmaxf(acc[rt][ct][reg] + bias, 0.f);
                }
            }
    }
}

// ---------------- K5: conv 3 (F3 rows, h3 kept in LDS) fused with conv 4 + classifier ----------------
__global__ __launch_bounds__(256) void k_conv34(const float* __restrict__ h2,
                                                const unsigned short* __restrict__ Wt,
                                                const float* __restrict__ bc,
                                                const int* __restrict__ offs,
                                                const int* __restrict__ ssrc,
                                                const int* __restrict__ L3,
                                                const int* __restrict__ meta,
                                                const float* __restrict__ Wc,
                                                const float* __restrict__ Wcls,
                                                const float* __restrict__ bcls,
                                                float* __restrict__ out) {
    __shared__ unsigned short sSb[32 * PAD];  // 8.7 KB
    __shared__ int sIdx[32][64];              // 8 KB
    __shared__ float sH3[32][Cn];             // 16 KB: h3 tile, fp32
    __shared__ short smap[Nn];                // 2 KB: node -> tile row
    __shared__ int snode[32], slo[32], scnt[32];
    __shared__ float sAgg[8][Cn];             // 4 KB
    __shared__ float sred[256];
    __shared__ int sI[256];
    int b = blockIdx.x, tid = threadIdx.x;
    int cnt3 = meta[2];
    int e1 = offs[1];                         // edges into node 0
    int lim = e1 < 256 ? e1 : 256;
    if (tid < lim) sI[tid] = ssrc[tid];

    int w = tid >> 6, lane = tid & 63, m = lane & 15, quad = lane >> 4;
    s16x8 bf0[4], bf1[4];
#pragma unroll
    for (int ks = 0; ks < 4; ++ks) {
        int ko = ks * 32 + quad * 8;
        bf0[ks] = *(const s16x8*)&Wt[(w * 32 + m) * Cn + ko];
        bf1[ks] = *(const s16x8*)&Wt[(w * 32 + 16 + m) * Cn + ko];
    }
    int c4 = tid & 31, u = tid >> 5;
    const float4* hb4 = (const float4*)(h2 + (size_t)b * (Nn * Cn));
    float4 aAgg = {0.f, 0.f, 0.f, 0.f};

    for (int tile = 0; tile * 32 < cnt3; ++tile) {
        __syncthreads();                      // protects sI (iter 0) and sH3/smap reuse
#pragma unroll
        for (int r = 0; r < 4; ++r) smap[tid + 256 * r] = -1;
        if (tid < 32) {
            int ti = tile * 32 + tid;
            int node = (ti < cnt3) ? L3[ti] : -1;
            snode[tid] = node;
            int lo = (node >= 0) ? offs[node] : 0;
            int hi = (node >= 0) ? offs[node + 1] : 0;
            slo[tid] = lo; scnt[tid] = hi - lo;
        }
        __syncthreads();
        if (tid < 32 && snode[tid] >= 0) smap[snode[tid]] = (short)tid;
#pragma unroll
        for (int r = 0; r < 8; ++r) {
            int row = w * 8 + r;
            int cnt = scnt[row];
            if (lane < cnt && lane < 64) sIdx[row][lane] = ssrc[slo[row] + lane];
        }
        __syncthreads();

        // gather h2 rows -> bf16 A-tile
#pragma unroll
        for (int t0 = 0; t0 < 4; ++t0) {
            int row = u * 4 + t0;
            int cnt = scnt[row], lo = slo[row];
            float4 a = {0.f, 0.f, 0.f, 0.f};
            int jm = cnt < 64 ? cnt : 64;
            for (int j = 0; j < jm; ++j) {
                float4 v = hb4[sIdx[row][j] * 32 + c4];
                a.x += v.x; a.y += v.y; a.z += v.z; a.w += v.w;
            }
            for (int j = 64; j < cnt; ++j) {  // rare overflow tail
                float4 v = hb4[ssrc[lo + j] * 32 + c4];
                a.x += v.x; a.y += v.y; a.z += v.z; a.w += v.w;
            }
            uint2 pk;
            pk.x = f2bf(a.x) | (f2bf(a.y) << 16);
            pk.y = f2bf(a.z) | (f2bf(a.w) << 16);
            *(uint2*)&sSb[row * PAD + c4 * 4] = pk;
        }
        __syncthreads();

        f32x4 acc[2][2];
#pragma unroll
        for (int rt = 0; rt < 2; ++rt)
#pragma unroll
            for (int ct = 0; ct < 2; ++ct) acc[rt][ct] = (f32x4){0.f, 0.f, 0.f, 0.f};
#pragma unroll
        for (int ks = 0; ks < 4; ++ks) {
            int ko = ks * 32 + quad * 8;
            s16x8 a0 = *(const s16x8*)&sSb[(0 * 16 + m) * PAD + ko];
            s16x8 a1 = *(const s16x8*)&sSb[(1 * 16 + m) * PAD + ko];
            acc[0][0] = __builtin_amdgcn_mfma_f32_16x16x32_bf16(a0, bf0[ks], acc[0][0], 0, 0, 0);
            acc[0][1] = __builtin_amdgcn_mfma_f32_16x16x32_bf16(a0, bf1[ks], acc[0][1], 0, 0, 0);
            acc[1][0] = __builtin_amdgcn_mfma_f32_16x16x32_bf16(a1, bf0[ks], acc[1][0], 0, 0, 0);
            acc[1][1] = __builtin_amdgcn_mfma_f32_16x16x32_bf16(a1, bf1[ks], acc[1][1], 0, 0, 0);
        }

        // h3 tile stays in LDS (same fp32 values as before)
#pragma unroll
        for (int rt = 0; rt < 2; ++rt)
#pragma unroll
            for (int ct = 0; ct < 2; ++ct) {
                int col = w * 32 + ct * 16 + m;
                float bias = bc[col];
#pragma unroll
                for (int reg = 0; reg < 4; ++reg) {
                    int row = rt * 16 + quad * 4 + reg;
                    sH3[row][col] = fmaxf(acc[rt][ct][reg] + bias, 0.f);
                }
            }
        __syncthreads();

        // conv4 aggregation: per-edge (handles multiplicity), restricted to this tile's rows
        for (int j = u; j < lim; j += 8) {
            int r2 = smap[sI[j]];
            if (r2 >= 0) {
                float4 v = *(const float4*)&sH3[r2][c4 * 4];
                aAgg.x += v.x; aAgg.y += v.y; aAgg.z += v.z; aAgg.w += v.w;
            }
        }
        for (int j = 256 + u; j < e1; j += 8) {  // rare overflow tail
            int r2 = smap[ssrc[j]];
            if (r2 >= 0) {
                float4 v = *(const float4*)&sH3[r2][c4 * 4];
                aAgg.x += v.x; aAgg.y += v.y; aAgg.z += v.z; aAgg.w += v.w;
            }
        }
    }

    *(float4*)&sAgg[u][c4 * 4] = aAgg;
    __syncthreads();
    int c = tid & 127, half = tid >> 7;
    if (tid < 128) {
        float s = sAgg[0][c];
#pragma unroll
        for (int q2 = 1; q2 < 8; ++q2) s += sAgg[q2][c];
        sAgg[0][c] = s;
    }
    __syncthreads();
    // split-k GEMV: 1x128 @ Wc (fp32 exact)
    float s = 0.f;
    int k0 = half * 64;
#pragma unroll 8
    for (int k = k0; k < k0 + 64; ++k) s += sAgg[0][k] * Wc[k * Cn + c];
    sred[tid] = s;
    __syncthreads();
    if (tid < 128) {
        float val = fmaxf(sred[c] + sred[128 + c] + bc[c], 0.f);
        sred[tid] = val * Wcls[c];
    }
    __syncthreads();
    for (int st = 64; st > 0; st >>= 1) {
        if (tid < st) sred[tid] += sred[tid + st];
        __syncthreads();
    }
    if (tid == 0) out[b] = sred[0] + bcls[0];
}

extern "C" void kernel_launch(void* const* d_in, const int* in_sizes, int n_in,
                              void* d_out, int out_size, void* d_ws, size_t ws_size,
                              hipStream_t stream) {
    const float* x    = (const float*)d_in[0];
    const int*   ei32 = (const int*)d_in[1];
    const float* We   = (const float*)d_in[2];
    const float* be   = (const float*)d_in[3];
    const float* Wc   = (const float*)d_in[4];
    const float* bc   = (const float*)d_in[5];
    const float* Wcls = (const float*)d_in[6];
    const float* bcls = (const float*)d_in[7];
    float* out = (float*)d_out;

    // ---- workspace layout ----
    // 0        g       32768   (B x C fp32)
    // 32768    indeg    4096
    // 36864    meta     4096   (meta[2]=|F3|; meta[3]=|F2|)
    // 40960    offs     8192
    // 49152    cursor   4096
    // 53248    ssrc    65536
    // 118784   edeg    65536   (fp32 degree per CSR-ordered edge)
    // 184320   L3       4096
    // 188416   L2       4096
    // 192512   Wt      32768   (128x128 bf16, transposed)
    // 225280   pws    131072   (embed partials)
    // 356352   f3       4096   (flag: ==1 means set; poison-tolerant)
    // 360448   f2       4096
    // 364544   epk     65536   (packed src|dst<<16 per edge)
    // 430080   hists   65536   (16 per-block histograms)
    // 495616   h2full  33554432 (fp32, sparse-filled at F2 rows)
    char* ws = (char*)d_ws;
    float*          g      = (float*)(ws + 0);
    int*            indeg  = (int*)(ws + 32768);
    int*            meta   = (int*)(ws + 36864);
    int*            offs   = (int*)(ws + 40960);
    int*            cursor = (int*)(ws + 49152);
    int*            ssrc   = (int*)(ws + 53248);
    float*          edeg   = (float*)(ws + 118784);
    int*            L3     = (int*)(ws + 184320);
    int*            L2     = (int*)(ws + 188416);
    unsigned short* Wt     = (unsigned short*)(ws + 192512);
    float*          pws    = (float*)(ws + 225280);
    int*            f3     = (int*)(ws + 356352);
    int*            f2     = (int*)(ws + 360448);
    unsigned int*   epk    = (unsigned int*)(ws + 364544);
    int*            hists  = (int*)(ws + 430080);
    float*          h2full = (float*)(ws + 495616);

    k_prep<<<336, 256, 0, stream>>>(x, We, Wc, ei32, pws, Wt, epk, hists, f3);
    k_mid<<<26, 1024, 0, stream>>>(hists, epk, f3, f2, indeg, offs, cursor, L3, meta,
                                   pws, be, Wc, g);
    k_scatter<<<17, 1024, 0, stream>>>(epk, indeg, cursor, ssrc, edeg, f2, L2, meta);
    k_conv2L<<<8 * Bn, 256, 0, stream>>>(g, h2full, Wt, bc, offs, edeg, L2, meta);
    k_conv34<<<Bn, 256, 0, stream>>>(h2full, Wt, bc, offs, ssrc, L3, meta, Wc, Wcls, bcls, out);
}

// Round 3
// 111.207 us; speedup vs baseline: 1.3377x; 1.1606x over previous
//
#include <hip/hip_runtime.h>
#include <cstdint>
#include <cstddef>

constexpr int Bn = 64;     // batch
constexpr int Nn = 1024;   // nodes per graph
constexpr int Dn = 1024;   // input feature dim
constexpr int Cn = 128;    // hidden channels
constexpr int En = 16384;  // edges per graph
constexpr int DMAX = 64;   // max tracked src-degree (Poisson mean 16; P(>=64) ~ 0; clamped)
constexpr int NB3 = 192;   // per-F3-node in-edge list capacity

typedef short s16x8 __attribute__((ext_vector_type(8)));   // 8 bf16 = 4 VGPR (MFMA A/B frag)
typedef float f32x4 __attribute__((ext_vector_type(4)));   // MFMA C/D frag

__device__ __forceinline__ uint32_t f2bf(float f) {        // fp32 -> bf16 bits, RNE
    uint32_t u = __float_as_uint(f);
    return (u + 0x7fffu + ((u >> 16) & 1u)) >> 16;
}

// ---------------- K1: embed partials (0..255) | Wt transpose (256..319) | hist+pack+F3 (320..335)
//                  | zero M (336..339) | zero n3cur+meta (340) ----------------
// F3/F2 flag semantics: set == store 1, test == (==1); ws poison (0xAA) reads as unset.
__global__ __launch_bounds__(256) void k_prep(const float* __restrict__ x,
                                              const float* __restrict__ We,
                                              const float* __restrict__ Wc,
                                              const int* __restrict__ ei32,
                                              float* __restrict__ pws,
                                              unsigned short* __restrict__ Wt,
                                              unsigned int* __restrict__ epk,
                                              int* __restrict__ hists,
                                              int* __restrict__ f3,
                                              int* __restrict__ Mm,
                                              int* __restrict__ n3cur,
                                              int* __restrict__ meta) {
    int bid = blockIdx.x, tid = threadIdx.x;
    if (bid < 256) {
        __shared__ float sx[256];
        __shared__ float sp[256];
        int b = bid >> 2, q = bid & 3;
        int c = tid & 127, h2 = tid >> 7;
        sx[tid] = x[b * Dn + q * 256 + tid];
        __syncthreads();
        float acc = 0.f;
        int d0 = q * 256 + h2 * 128;
        int dl = h2 * 128;
#pragma unroll 8
        for (int i = 0; i < 128; ++i) acc += sx[dl + i] * We[(d0 + i) * Cn + c];
        sp[h2 * 128 + c] = acc;
        __syncthreads();
        if (h2 == 0) pws[(b * 4 + q) * Cn + c] = sp[c] + sp[128 + c];
    } else if (bid < 320) {
        int i = (bid - 256) * 256 + tid;        // [0, 16384)
        int n = i >> 7, k = i & 127;
        Wt[i] = (unsigned short)f2bf(Wc[k * Cn + n]);
    } else if (bid < 336) {
        int hb = bid - 320;                     // 16 hist blocks, 1024 edges each
        __shared__ int hloc[Nn];
        __shared__ int det;
#pragma unroll
        for (int r = 0; r < 4; ++r) hloc[r * 256 + tid] = 0;
        if (tid == 0) det = 0;
        __syncthreads();
        int base = hb * 1024;
        int hw = 0;
#pragma unroll
        for (int r = 0; r < 4; ++r) { int i = base + r * 256 + tid; hw |= ei32[2 * i + 1]; }
        if (hw) atomicOr(&det, 1);
        __syncthreads();
        bool i64 = (det == 0);                  // int64 input => high dwords all zero
#pragma unroll
        for (int r = 0; r < 4; ++r) {
            int i = base + r * 256 + tid;
            int s, d;
            if (i64) {
                s = ((const int2*)ei32)[i].x & (Nn - 1);
                d = ((const int2*)ei32)[En + i].x & (Nn - 1);
            } else {
                s = ei32[i] & (Nn - 1);
                d = ei32[En + i] & (Nn - 1);
            }
            epk[i] = (unsigned)s | ((unsigned)d << 16);
            atomicAdd(&hloc[d], 1);
            if (d == 0) f3[s] = 1;              // benign race: all writers store 1
        }
        __syncthreads();
#pragma unroll
        for (int r = 0; r < 4; ++r) hists[hb * Nn + r * 256 + tid] = hloc[r * 256 + tid];
    } else if (bid < 340) {
        // zero M (1024 x 64 ints = 256 KB) with int4 stores
        int4 z = {0, 0, 0, 0};
        int4* M4 = (int4*)Mm;
#pragma unroll
        for (int r = 0; r < 16; ++r) M4[(bid - 336) * 4096 + r * 256 + tid] = z;
    } else {
        // zero n3cur (1024 ints) + meta counters
        int4 z = {0, 0, 0, 0};
        ((int4*)n3cur)[tid] = z;
        if (tid == 0) meta[4] = 0;              // e0 cursor
    }
}

// ---------------- K2: edge pass (b0..15): M[d][deg(s)]++, f2 mark, n3/e0 lists
//                  | L3 compact (b16) | g GEMV (b17..24) ----------------
__global__ __launch_bounds__(1024) void k_build(const int* __restrict__ hists,
                                                const unsigned int* __restrict__ epk,
                                                const int* __restrict__ f3,
                                                int* __restrict__ f2,
                                                int* __restrict__ Mm,
                                                int* __restrict__ n3cur,
                                                int* __restrict__ n3src,
                                                int* __restrict__ e0,
                                                int* __restrict__ L3,
                                                int* __restrict__ meta,
                                                const float* __restrict__ pws,
                                                const float* __restrict__ be,
                                                const float* __restrict__ Wc,
                                                float* __restrict__ g) {
    int bid = blockIdx.x, t = threadIdx.x;
    if (bid < 16) {
        __shared__ int sInd[Nn];
        int v = 0;
#pragma unroll
        for (int h = 0; h < 16; ++h) v += hists[h * Nn + t];
        sInd[t] = v;
        __syncthreads();
        unsigned e = epk[bid * 1024 + t];
        int s = e & 0xffff, d = e >> 16;
        int dd = sInd[s]; if (dd > DMAX - 1) dd = DMAX - 1;
        atomicAdd(&Mm[d * DMAX + dd], 1);
        if (f3[d] == 1) {
            f2[s] = 1;
            int p = atomicAdd(&n3cur[d], 1);
            if (p < NB3) n3src[d * NB3 + p] = s;
        }
        if (d == 0) {
            int p = atomicAdd(&meta[4], 1);
            if (p < 1024) e0[p] = s;
        }
    } else if (bid == 16) {
        __shared__ int c3;
        if (t == 0) c3 = 0;
        __syncthreads();
        if (f3[t] == 1) { int p = atomicAdd(&c3, 1); L3[p] = t; }
        __syncthreads();
        if (t == 0) meta[2] = c3;
    } else {
        // g[b][c] = sum_k relu(e)[b][k] * Wc[k][c]; 8 blocks x 8 b each
        __shared__ float se[8][Cn];
        int blk = bid - 17, bi = t >> 7, c = t & 127, b = blk * 8 + bi;
        float e4 = pws[(b * 4 + 0) * Cn + c] + pws[(b * 4 + 1) * Cn + c] +
                   pws[(b * 4 + 2) * Cn + c] + pws[(b * 4 + 3) * Cn + c] + be[c];
        se[bi][c] = fmaxf(e4, 0.f);
        __syncthreads();
        float acc = 0.f;
#pragma unroll 8
        for (int k = 0; k < Cn; ++k) acc += se[bi][k] * Wc[k * Cn + c];
        g[b * Cn + c] = acc;
    }
}

constexpr int PAD = 136;     // LDS row stride in bf16 elems (128-wide tiles)
constexpr int PADR = 72;     // LDS row stride in bf16 elems (64-wide tiles)

// ---------------- K3: conv 1+2 via degree-histogram double-MFMA, frontier-restricted ----------------
// A1[n,:] = M[n,:] @ R_b  (R_b[d][c] = relu(d*g[b,c]+bc[c]));  h2 = relu(A1 @ Wc + bc)
// Each block compacts f2 -> L2 deterministically (order-preserving), so all blocks agree.
__global__ __launch_bounds__(256, 4) void k_conv2M(const float* __restrict__ g,
                                                   float* __restrict__ h2,
                                                   const unsigned short* __restrict__ Wt,
                                                   const float* __restrict__ bc,
                                                   const int* __restrict__ Mm,
                                                   const int* __restrict__ f2) {
    int bidx = blockIdx.x;
    int tile0 = bidx >> 6, b = bidx & 63;     // blocks with same b stay on XCD b%8
    __shared__ int sL2[Nn];                   // 4 KB
    __shared__ int sWs[4];
    __shared__ unsigned short sRt[128 * PADR]; // 18 KB: R transposed [col][d]
    __shared__ unsigned short sMb[32 * PADR];  // 4.5 KB: M tile bf16
    __shared__ unsigned short sSb[32 * PAD];   // 8.7 KB: A1 tile bf16
    __shared__ int snode[32];
    int tid = threadIdx.x, lane = tid & 63, w = tid >> 6;
    int m = lane & 15, quad = lane >> 4;

    // ---- deterministic order-preserving compaction of f2 -> sL2 ----
    int n0 = tid * 4;
    int fl0 = (f2[n0] == 1), fl1 = (f2[n0 + 1] == 1), fl2 = (f2[n0 + 2] == 1), fl3 = (f2[n0 + 3] == 1);
    int c = fl0 + fl1 + fl2 + fl3;
    int inc = c;
    for (int off = 1; off < 64; off <<= 1) {
        int nv = __shfl_up(inc, off);
        if (lane >= off) inc += nv;
    }
    if (lane == 63) sWs[w] = inc;
    __syncthreads();
    int wbase = 0;
#pragma unroll
    for (int q = 0; q < 4; ++q) wbase += (q < w) ? sWs[q] : 0;
    int cnt2 = sWs[0] + sWs[1] + sWs[2] + sWs[3];
    int pos = wbase + inc - c;
    if (fl0) sL2[pos++] = n0;
    if (fl1) sL2[pos++] = n0 + 1;
    if (fl2) sL2[pos++] = n0 + 2;
    if (fl3) sL2[pos++] = n0 + 3;

    // ---- build R_b transposed in LDS ----
    {
        int cc = tid & 127, dh = tid >> 7;
        float gc = g[b * Cn + cc], bcc = bc[cc];
#pragma unroll
        for (int d = dh * 32; d < dh * 32 + 32; ++d) {
            float r = fmaxf(fmaf((float)d, gc, bcc), 0.f);
            sRt[cc * PADR + d] = (unsigned short)f2bf(r);
        }
    }

    // Wt B-frags (tile-invariant)
    s16x8 bf0[4], bf1[4];
#pragma unroll
    for (int ks = 0; ks < 4; ++ks) {
        int ko = ks * 32 + quad * 8;
        bf0[ks] = *(const s16x8*)&Wt[(w * 32 + m) * Cn + ko];
        bf1[ks] = *(const s16x8*)&Wt[(w * 32 + 16 + m) * Cn + ko];
    }
    __syncthreads();

    for (int tile = tile0; tile * 32 < cnt2; tile += 8) {
        __syncthreads();                      // protect sMb/sSb/snode reuse
        if (tid < 32) {
            int ti = tile * 32 + tid;
            snode[tid] = (ti < cnt2) ? sL2[ti] : -1;
        }
        __syncthreads();
        // stage M rows (int) -> bf16 tile
        {
            int row = tid >> 3, seg = tid & 7;
            int node = snode[row];
            unsigned short pk[8];
            if (node >= 0) {
                const int4* mp = (const int4*)&Mm[node * DMAX + seg * 8];
                int4 a = mp[0], bq = mp[1];
                pk[0] = (unsigned short)f2bf((float)a.x);
                pk[1] = (unsigned short)f2bf((float)a.y);
                pk[2] = (unsigned short)f2bf((float)a.z);
                pk[3] = (unsigned short)f2bf((float)a.w);
                pk[4] = (unsigned short)f2bf((float)bq.x);
                pk[5] = (unsigned short)f2bf((float)bq.y);
                pk[6] = (unsigned short)f2bf((float)bq.z);
                pk[7] = (unsigned short)f2bf((float)bq.w);
            } else {
#pragma unroll
                for (int i = 0; i < 8; ++i) pk[i] = 0;
            }
            *(uint4*)&sMb[row * PADR + seg * 8] = *(uint4*)pk;
        }
        __syncthreads();

        // MFMA-1: A1(32x128) = Mtile(32x64) @ R(64x128)
        f32x4 acc1[2][2];
#pragma unroll
        for (int rt = 0; rt < 2; ++rt)
#pragma unroll
            for (int ct = 0; ct < 2; ++ct) acc1[rt][ct] = (f32x4){0.f, 0.f, 0.f, 0.f};
#pragma unroll
        for (int ks = 0; ks < 2; ++ks) {
            int ko = ks * 32 + quad * 8;
            s16x8 a0 = *(const s16x8*)&sMb[m * PADR + ko];
            s16x8 a1 = *(const s16x8*)&sMb[(16 + m) * PADR + ko];
            s16x8 r0 = *(const s16x8*)&sRt[(w * 32 + m) * PADR + ko];
            s16x8 r1 = *(const s16x8*)&sRt[(w * 32 + 16 + m) * PADR + ko];
            acc1[0][0] = __builtin_amdgcn_mfma_f32_16x16x32_bf16(a0, r0, acc1[0][0], 0, 0, 0);
            acc1[0][1] = __builtin_amdgcn_mfma_f32_16x16x32_bf16(a0, r1, acc1[0][1], 0, 0, 0);
            acc1[1][0] = __builtin_amdgcn_mfma_f32_16x16x32_bf16(a1, r0, acc1[1][0], 0, 0, 0);
            acc1[1][1] = __builtin_amdgcn_mfma_f32_16x16x32_bf16(a1, r1, acc1[1][1], 0, 0, 0);
        }
        // spill A1 -> bf16 A-tile
#pragma unroll
        for (int rt = 0; rt < 2; ++rt)
#pragma unroll
            for (int ct = 0; ct < 2; ++ct) {
                int col = w * 32 + ct * 16 + m;
#pragma unroll
                for (int reg = 0; reg < 4; ++reg) {
                    int row = rt * 16 + quad * 4 + reg;
                    sSb[row * PAD + col] = (unsigned short)f2bf(acc1[rt][ct][reg]);
                }
            }
        __syncthreads();

        // MFMA-2: h2 = relu(A1 @ Wc + bc)
        f32x4 acc[2][2];
#pragma unroll
        for (int rt = 0; rt < 2; ++rt)
#pragma unroll
            for (int ct = 0; ct < 2; ++ct) acc[rt][ct] = (f32x4){0.f, 0.f, 0.f, 0.f};
#pragma unroll
        for (int ks = 0; ks < 4; ++ks) {
            int ko = ks * 32 + quad * 8;
            s16x8 a0 = *(const s16x8*)&sSb[(0 * 16 + m) * PAD + ko];
            s16x8 a1 = *(const s16x8*)&sSb[(1 * 16 + m) * PAD + ko];
            acc[0][0] = __builtin_amdgcn_mfma_f32_16x16x32_bf16(a0, bf0[ks], acc[0][0], 0, 0, 0);
            acc[0][1] = __builtin_amdgcn_mfma_f32_16x16x32_bf16(a0, bf1[ks], acc[0][1], 0, 0, 0);
            acc[1][0] = __builtin_amdgcn_mfma_f32_16x16x32_bf16(a1, bf0[ks], acc[1][0], 0, 0, 0);
            acc[1][1] = __builtin_amdgcn_mfma_f32_16x16x32_bf16(a1, bf1[ks], acc[1][1], 0, 0, 0);
        }

#pragma unroll
        for (int rt = 0; rt < 2; ++rt)
#pragma unroll
            for (int ct = 0; ct < 2; ++ct) {
                int col = w * 32 + ct * 16 + m;
                float bias = bc[col];
#pragma unroll
                for (int reg = 0; reg < 4; ++reg) {
                    int row = rt * 16 + quad * 4 + reg;
                    int node = snode[row];
                    if (node >= 0)
                        h2[((size_t)b * Nn + node) * Cn + col] = fmaxf(acc[rt][ct][reg] + bias, 0.f);
                }
            }
    }
}

// ---------------- K4: conv 3 (F3 rows, h3 in LDS) fused with conv 4 + classifier ----------------
__global__ __launch_bounds__(256) void k_conv34(const float* __restrict__ h2,
                                                const unsigned short* __restrict__ Wt,
                                                const float* __restrict__ bc,
                                                const int* __restrict__ L3,
                                                const int* __restrict__ meta,
                                                const int* __restrict__ n3cur,
                                                const int* __restrict__ n3src,
                                                const int* __restrict__ e0,
                                                const float* __restrict__ Wc,
                                                const float* __restrict__ Wcls,
                                                const float* __restrict__ bcls,
                                                float* __restrict__ out) {
    __shared__ unsigned short sSb[32 * PAD];  // 8.7 KB
    __shared__ int sIdx[32][64];              // 8 KB
    __shared__ float sH3[32][Cn];             // 16 KB: h3 tile, fp32
    __shared__ short smap[Nn];                // 2 KB: node -> tile row
    __shared__ int snode[32], scnt[32];
    __shared__ float sAgg[8][Cn];             // 4 KB
    __shared__ float sred[256];
    __shared__ int sI[256];
    int b = blockIdx.x, tid = threadIdx.x;
    int cnt3 = meta[2];
    int m0 = meta[4]; if (m0 > 1024) m0 = 1024;   // edges into node 0
    int lim = m0 < 256 ? m0 : 256;
    if (tid < lim) sI[tid] = e0[tid];

    int w = tid >> 6, lane = tid & 63, m = lane & 15, quad = lane >> 4;
    s16x8 bf0[4], bf1[4];
#pragma unroll
    for (int ks = 0; ks < 4; ++ks) {
        int ko = ks * 32 + quad * 8;
        bf0[ks] = *(const s16x8*)&Wt[(w * 32 + m) * Cn + ko];
        bf1[ks] = *(const s16x8*)&Wt[(w * 32 + 16 + m) * Cn + ko];
    }
    int c4 = tid & 31, u = tid >> 5;
    const float4* hb4 = (const float4*)(h2 + (size_t)b * (Nn * Cn));
    float4 aAgg = {0.f, 0.f, 0.f, 0.f};

    for (int tile = 0; tile * 32 < cnt3; ++tile) {
        __syncthreads();                      // protects sI (iter 0) and sH3/smap reuse
#pragma unroll
        for (int r = 0; r < 4; ++r) smap[tid + 256 * r] = -1;
        if (tid < 32) {
            int ti = tile * 32 + tid;
            int node = (ti < cnt3) ? L3[ti] : -1;
            snode[tid] = node;
            int cnt = (node >= 0) ? n3cur[node] : 0;
            if (cnt > NB3) cnt = NB3;
            scnt[tid] = cnt;
        }
        __syncthreads();
        if (tid < 32 && snode[tid] >= 0) smap[snode[tid]] = (short)tid;
#pragma unroll
        for (int r = 0; r < 8; ++r) {
            int row = w * 8 + r;
            int cnt = scnt[row];
            if (lane < cnt && lane < 64) sIdx[row][lane] = n3src[snode[row] * NB3 + lane];
        }
        __syncthreads();

        // gather h2 rows -> bf16 A-tile
#pragma unroll
        for (int t0 = 0; t0 < 4; ++t0) {
            int row = u * 4 + t0;
            int cnt = scnt[row];
            float4 a = {0.f, 0.f, 0.f, 0.f};
            int jm = cnt < 64 ? cnt : 64;
            for (int j = 0; j < jm; ++j) {
                float4 v = hb4[sIdx[row][j] * 32 + c4];
                a.x += v.x; a.y += v.y; a.z += v.z; a.w += v.w;
            }
            for (int j = 64; j < cnt; ++j) {  // rare overflow tail
                float4 v = hb4[n3src[snode[row] * NB3 + j] * 32 + c4];
                a.x += v.x; a.y += v.y; a.z += v.z; a.w += v.w;
            }
            uint2 pk;
            pk.x = f2bf(a.x) | (f2bf(a.y) << 16);
            pk.y = f2bf(a.z) | (f2bf(a.w) << 16);
            *(uint2*)&sSb[row * PAD + c4 * 4] = pk;
        }
        __syncthreads();

        f32x4 acc[2][2];
#pragma unroll
        for (int rt = 0; rt < 2; ++rt)
#pragma unroll
            for (int ct = 0; ct < 2; ++ct) acc[rt][ct] = (f32x4){0.f, 0.f, 0.f, 0.f};
#pragma unroll
        for (int ks = 0; ks < 4; ++ks) {
            int ko = ks * 32 + quad * 8;
            s16x8 a0 = *(const s16x8*)&sSb[(0 * 16 + m) * PAD + ko];
            s16x8 a1 = *(const s16x8*)&sSb[(1 * 16 + m) * PAD + ko];
            acc[0][0] = __builtin_amdgcn_mfma_f32_16x16x32_bf16(a0, bf0[ks], acc[0][0], 0, 0, 0);
            acc[0][1] = __builtin_amdgcn_mfma_f32_16x16x32_bf16(a0, bf1[ks], acc[0][1], 0, 0, 0);
            acc[1][0] = __builtin_amdgcn_mfma_f32_16x16x32_bf16(a1, bf0[ks], acc[1][0], 0, 0, 0);
            acc[1][1] = __builtin_amdgcn_mfma_f32_16x16x32_bf16(a1, bf1[ks], acc[1][1], 0, 0, 0);
        }

        // h3 tile stays in LDS (fp32)
#pragma unroll
        for (int rt = 0; rt < 2; ++rt)
#pragma unroll
            for (int ct = 0; ct < 2; ++ct) {
                int col = w * 32 + ct * 16 + m;
                float bias = bc[col];
#pragma unroll
                for (int reg = 0; reg < 4; ++reg) {
                    int row = rt * 16 + quad * 4 + reg;
                    sH3[row][col] = fmaxf(acc[rt][ct][reg] + bias, 0.f);
                }
            }
        __syncthreads();

        // conv4 aggregation: per-edge (handles multiplicity), restricted to this tile's rows
        for (int j = u; j < lim; j += 8) {
            int r2 = smap[sI[j]];
            if (r2 >= 0) {
                float4 v = *(const float4*)&sH3[r2][c4 * 4];
                aAgg.x += v.x; aAgg.y += v.y; aAgg.z += v.z; aAgg.w += v.w;
            }
        }
        for (int j = 256 + u; j < m0; j += 8) {  // rare overflow tail
            int r2 = smap[e0[j]];
            if (r2 >= 0) {
                float4 v = *(const float4*)&sH3[r2][c4 * 4];
                aAgg.x += v.x; aAgg.y += v.y; aAgg.z += v.z; aAgg.w += v.w;
            }
        }
    }

    *(float4*)&sAgg[u][c4 * 4] = aAgg;
    __syncthreads();
    int c = tid & 127, half = tid >> 7;
    if (tid < 128) {
        float s = sAgg[0][c];
#pragma unroll
        for (int q2 = 1; q2 < 8; ++q2) s += sAgg[q2][c];
        sAgg[0][c] = s;
    }
    __syncthreads();
    // split-k GEMV: 1x128 @ Wc (fp32 exact)
    float s = 0.f;
    int k0 = half * 64;
#pragma unroll 8
    for (int k = k0; k < k0 + 64; ++k) s += sAgg[0][k] * Wc[k * Cn + c];
    sred[tid] = s;
    __syncthreads();
    if (tid < 128) {
        float val = fmaxf(sred[c] + sred[128 + c] + bc[c], 0.f);
        sred[tid] = val * Wcls[c];
    }
    __syncthreads();
    for (int st = 64; st > 0; st >>= 1) {
        if (tid < st) sred[tid] += sred[tid + st];
        __syncthreads();
    }
    if (tid == 0) out[b] = sred[0] + bcls[0];
}

extern "C" void kernel_launch(void* const* d_in, const int* in_sizes, int n_in,
                              void* d_out, int out_size, void* d_ws, size_t ws_size,
                              hipStream_t stream) {
    const float* x    = (const float*)d_in[0];
    const int*   ei32 = (const int*)d_in[1];
    const float* We   = (const float*)d_in[2];
    const float* be   = (const float*)d_in[3];
    const float* Wc   = (const float*)d_in[4];
    const float* bc   = (const float*)d_in[5];
    const float* Wcls = (const float*)d_in[6];
    const float* bcls = (const float*)d_in[7];
    float* out = (float*)d_out;

    // ---- workspace layout ----
    // 0        g       32768   (B x C fp32)
    // 32768    meta     4096   (meta[2]=|F3|; meta[4]=|e0|)
    // 36864    e0       4096   (node-0 src list, cap 1024)
    // 40960    n3cur    4096   (per-F3-node list cursor)
    // 45056    Wt      32768   (128x128 bf16, transposed)
    // 77824    pws    131072   (embed partials)
    // 208896   f3       4096   (flag: ==1 means set; poison-tolerant)
    // 212992   f2       4096
    // 217088   epk     65536   (packed src|dst<<16 per edge)
    // 282624   hists   65536   (16 per-block histograms)
    // 348160   M      262144   (1024 x 64 int degree-count matrix)
    // 610304   n3src  786432   (1024 x 192 int in-edge lists, F3 nodes only)
    // 1396736  L3       4096
    // 1400832  h2full 33554432 (fp32, sparse-filled at F2 rows)
    char* ws = (char*)d_ws;
    float*          g      = (float*)(ws + 0);
    int*            meta   = (int*)(ws + 32768);
    int*            e0     = (int*)(ws + 36864);
    int*            n3cur  = (int*)(ws + 40960);
    unsigned short* Wt     = (unsigned short*)(ws + 45056);
    float*          pws    = (float*)(ws + 77824);
    int*            f3     = (int*)(ws + 208896);
    int*            f2     = (int*)(ws + 212992);
    unsigned int*   epk    = (unsigned int*)(ws + 217088);
    int*            hists  = (int*)(ws + 282624);
    int*            Mm     = (int*)(ws + 348160);
    int*            n3src  = (int*)(ws + 610304);
    int*            L3     = (int*)(ws + 1396736);
    float*          h2full = (float*)(ws + 1400832);

    k_prep<<<341, 256, 0, stream>>>(x, We, Wc, ei32, pws, Wt, epk, hists, f3, Mm, n3cur, meta);
    k_build<<<25, 1024, 0, stream>>>(hists, epk, f3, f2, Mm, n3cur, n3src, e0, L3, meta,
                                     pws, be, Wc, g);
    k_conv2M<<<8 * Bn, 256, 0, stream>>>(g, h2full, Wt, bc, Mm, f2);
    k_conv34<<<Bn, 256, 0, stream>>>(h2full, Wt, bc, L3, meta, n3cur, n3src, e0,
                                     Wc, Wcls, bcls, out);
}